// Round 5
// baseline (384.448 us; speedup 1.0000x reference)
//
#include <hip/hip_runtime.h>
#include <math.h>

namespace {

constexpr int kRows = 4096;
constexpr int kNF   = 65;
constexpr int kNE   = 256;
constexpr int kNH   = 8;
constexpr int kNC   = 64;                  // kNF - 1 fields used
constexpr int kXRow = kNF * kNE;           // 16640 floats per x row
constexpr int kORow = (kNF + kNH) * kNE;   // 18688 floats per out row

// w2[h*32+d] = sum_k bw[h,d,k] * query[h,k]
__global__ __launch_bounds__(256) void w2_precompute(
    const float* __restrict__ bw, const float* __restrict__ query,
    float* __restrict__ w2) {
  const int t = threadIdx.x;         // t = h*32 + d
  const int h = t >> 5;
  const float4* __restrict__ b4 = reinterpret_cast<const float4*>(bw) + (size_t)t * 64;
  const float4* __restrict__ q4 = reinterpret_cast<const float4*>(query) + (size_t)h * 64;
  float acc = 0.f;
#pragma unroll 8
  for (int k = 0; k < 64; ++k) {
    const float4 b = b4[k];
    const float4 q = q4[k];
    acc += b.x * q.x + b.y * q.y + b.z * q.z + b.w * q.w;
  }
  w2[t] = acc;
}

// One block = one row, 512 threads = 8 waves. Wave wv owns fields c=8wv..8wv+7;
// thread holds its e-quad of each: kreg[8] = 32 VGPRs. Peak live ~60 VGPRs ->
// fits the 64-VGPR/8-waves-per-SIMD budget with NO spill (rounds 3/4 failure:
// kreg[16]=64 live into a 64-reg budget -> scratch traffic). LDS 37 KB ->
// 4 blocks/CU x 8 waves = 32 waves/CU (100% occupancy target).
__global__ __attribute__((amdgpu_flat_work_group_size(512, 512),
                          amdgpu_waves_per_eu(8, 8)))
void fused_row(
    const float* __restrict__ x, const float* __restrict__ w2g,
    const float* __restrict__ vals, float* __restrict__ out) {
  __shared__ float att_t[kNC * 9];        // [c][h] stride 9: conflict-free
  __shared__ float cw[kNC * kNH];         // [c][h], 2 KB
  __shared__ float4 part[8 * 4 * 64];     // [slot][head][equad], 32 KB

  const int tid  = threadIdx.x;
  const int wv   = tid >> 6;
  const int lane = tid & 63;
  const int r    = blockIdx.x;

  const float* __restrict__ xrow = x + (size_t)r * kXRow;
  float* __restrict__ orow       = out + (size_t)r * kORow;
  const float4* __restrict__ x4  = reinterpret_cast<const float4*>(xrow);
  float4* __restrict__ o4        = reinterpret_cast<float4*>(orow);

  // ---- phase A: single coalesced read; copy -> out; keys -> regs; att fused.
  //      Lane's w2 quad comes straight from global (L2-hot broadcast): head
  //      h = lane>>3, dims 4*(lane&7)..+3; 3-level shfl reduces over lane&7.
  float4 kreg[8];
  const float4 wq = reinterpret_cast<const float4*>(w2g)[lane];
  if (wv == 0) o4[lane] = x4[lane];     // field 0: copy only (not a key)
#pragma unroll
  for (int j = 0; j < 8; ++j) {
    const int c = wv * 8 + j;           // key index; field f = c+1
    const float4 v = x4[(c + 1) * 64 + lane];
    o4[(c + 1) * 64 + lane] = v;
    kreg[j] = v;
    float p = v.x * wq.x + v.y * wq.y + v.z * wq.z + v.w * wq.w;
    p += __shfl_xor(p, 1);
    p += __shfl_xor(p, 2);
    p += __shfl_xor(p, 4);
    if ((lane & 7) == 0) att_t[c * 9 + (lane >> 3)] = p * 0.03125f;
  }
  __syncthreads();

  // ---- entmax-1.5 bisection, run redundantly by ALL 8 waves (identical
  //      inputs/ops -> bitwise-identical results; cw writes are a benign
  //      identical-value race; each wave reads back its own writes so no
  //      barrier is needed before phase C). lane = h*8+kk, 8 c's per lane.
  {
    const int h  = lane >> 3;
    const int kk = lane & 7;
    float X[8];
#pragma unroll
    for (int j = 0; j < 8; ++j) X[j] = att_t[(kk * 8 + j) * 9 + h];

    float mx = X[0];
#pragma unroll
    for (int j = 1; j < 8; ++j) mx = fmaxf(mx, X[j]);
    mx = fmaxf(mx, __shfl_xor(mx, 1));
    mx = fmaxf(mx, __shfl_xor(mx, 2));
    mx = fmaxf(mx, __shfl_xor(mx, 4));

    float tau_lo = mx - 1.0f;       // _gp(1, 1.5) = 1
    float dm     = 0.875f;          // 1 - (1/64)^0.5
    float f_lo = 0.f;
#pragma unroll
    for (int j = 0; j < 8; ++j) {
      float t = fmaxf(X[j] - tau_lo, 0.f);
      f_lo += t * t;
    }
    f_lo += __shfl_xor(f_lo, 1);
    f_lo += __shfl_xor(f_lo, 2);
    f_lo += __shfl_xor(f_lo, 4);
    f_lo -= 1.0f;

    float tau_m = tau_lo;
    for (int it = 0; it < 50; ++it) {
      dm *= 0.5f;
      tau_m = tau_lo + dm;
      float fm = 0.f;
#pragma unroll
      for (int j = 0; j < 8; ++j) {
        float t = fmaxf(X[j] - tau_m, 0.f);
        fm += t * t;
      }
      fm += __shfl_xor(fm, 1);
      fm += __shfl_xor(fm, 2);
      fm += __shfl_xor(fm, 4);
      fm -= 1.0f;
      tau_lo = (fm * f_lo >= 0.f) ? tau_m : tau_lo;
      // fp32 fixed point: once tau_lo + dm/2 rounds to tau_lo for every lane,
      // all remaining reference iterations are bitwise no-ops with final
      // tau_m == tau_lo. Exact fp32 semantics preserved (verified rounds 1-4).
      if (__all(tau_lo + dm * 0.5f == tau_lo)) {
        tau_m = tau_lo;
        break;
      }
    }

    float p[8];
    float s = 0.f;
#pragma unroll
    for (int j = 0; j < 8; ++j) {
      float t = fmaxf(X[j] - tau_m, 0.f);
      p[j] = t * t;
      s += p[j];
    }
    s += __shfl_xor(s, 1);
    s += __shfl_xor(s, 2);
    s += __shfl_xor(s, 4);
    const float inv = 1.0f / s;
    // vals slice for (h, c=kk*8..kk*8+7): 8 consecutive floats, L2-hot.
    const float4 vv0 = *reinterpret_cast<const float4*>(vals + h * kNC + kk * 8);
    const float4 vv1 = *reinterpret_cast<const float4*>(vals + h * kNC + kk * 8 + 4);
    const float vv[8] = {vv0.x, vv0.y, vv0.z, vv0.w, vv1.x, vv1.y, vv1.z, vv1.w};
#pragma unroll
    for (int j = 0; j < 8; ++j) {
      const int c = kk * 8 + j;
      cw[c * kNH + h] = p[j] * inv * vv[j];
    }
  }
  // no barrier: each wave reads back only cw values it wrote itself.

  // ---- phase C: 2 passes of 4 heads. Per pass: per-wave partial from
  //      register keys -> part[wv] -> barrier -> 512-thread sum of 8 slots
  //      + exp + coalesced store.
  const float4* __restrict__ cw4 = reinterpret_cast<const float4*>(cw);
  const float2* part2            = reinterpret_cast<const float2*>(part);
#pragma unroll
  for (int hh = 0; hh < 2; ++hh) {
    float4 acc[4];
#pragma unroll
    for (int i = 0; i < 4; ++i) acc[i] = make_float4(0.f, 0.f, 0.f, 0.f);
#pragma unroll
    for (int j = 0; j < 8; ++j) {
      const float4 kv = kreg[j];
      const float4 ca = cw4[(wv * 8 + j) * 2 + hh];   // broadcast
      acc[0].x += ca.x * kv.x; acc[0].y += ca.x * kv.y; acc[0].z += ca.x * kv.z; acc[0].w += ca.x * kv.w;
      acc[1].x += ca.y * kv.x; acc[1].y += ca.y * kv.y; acc[1].z += ca.y * kv.z; acc[1].w += ca.y * kv.w;
      acc[2].x += ca.z * kv.x; acc[2].y += ca.z * kv.y; acc[2].z += ca.z * kv.z; acc[2].w += ca.z * kv.w;
      acc[3].x += ca.w * kv.x; acc[3].y += ca.w * kv.y; acc[3].z += ca.w * kv.z; acc[3].w += ca.w * kv.w;
    }
#pragma unroll
    for (int i = 0; i < 4; ++i) {
      part[wv * 256 + i * 64 + lane] = acc[i];   // lane-consecutive, conflict-free
    }
    __syncthreads();
    // final: o = tid covers (head i = o>>7, within-head float2 o&127)
    {
      const int o = tid;
      float2 s = part2[o];
#pragma unroll
      for (int sl = 1; sl < 8; ++sl) {
        const float2 t = part2[sl * 512 + o];
        s.x += t.x; s.y += t.y;
      }
      float2 e;
      e.x = expf(s.x);
      e.y = expf(s.y);
      *reinterpret_cast<float2*>(
          &orow[kXRow + (hh * 4 + (o >> 7)) * kNE + (o & 127) * 2]) = e;
    }
    __syncthreads();   // protect part reuse by next pass
  }
}

}  // namespace

extern "C" void kernel_launch(void* const* d_in, const int* in_sizes, int n_in,
                              void* d_out, int out_size, void* d_ws, size_t ws_size,
                              hipStream_t stream) {
  const float* x     = reinterpret_cast<const float*>(d_in[0]);
  const float* bw    = reinterpret_cast<const float*>(d_in[1]);
  const float* query = reinterpret_cast<const float*>(d_in[2]);
  const float* vals  = reinterpret_cast<const float*>(d_in[3]);
  float* out = reinterpret_cast<float*>(d_out);
  float* w2  = reinterpret_cast<float*>(d_ws);   // 256 floats of scratch

  hipLaunchKernelGGL(w2_precompute, dim3(1), dim3(256), 0, stream, bw, query, w2);
  hipLaunchKernelGGL(fused_row, dim3(kRows), dim3(512), 0, stream, x, w2, vals, out);
}

// Round 6
// 146.917 us; speedup vs baseline: 2.6168x; 2.6168x over previous
//
#include <hip/hip_runtime.h>
#include <math.h>

namespace {

constexpr int kRows = 4096;
constexpr int kNF   = 65;
constexpr int kNE   = 256;
constexpr int kNH   = 8;
constexpr int kNC   = 64;                  // kNF - 1 fields used
constexpr int kXRow = kNF * kNE;           // 16640 floats per x row
constexpr int kORow = (kNF + kNH) * kNE;   // 18688 floats per out row

// w2[h*32+d] = sum_k bw[h,d,k] * query[h,k]
__global__ __launch_bounds__(256) void w2_precompute(
    const float* __restrict__ bw, const float* __restrict__ query,
    float* __restrict__ w2) {
  const int t = threadIdx.x;         // t = h*32 + d
  const int h = t >> 5;
  const float4* __restrict__ b4 = reinterpret_cast<const float4*>(bw) + (size_t)t * 64;
  const float4* __restrict__ q4 = reinterpret_cast<const float4*>(query) + (size_t)h * 64;
  float acc = 0.f;
#pragma unroll 8
  for (int k = 0; k < 64; ++k) {
    const float4 b = b4[k];
    const float4 q = q4[k];
    acc += b.x * q.x + b.y * q.y + b.z * q.z + b.w * q.w;
  }
  w2[t] = acc;
}

// One block = one row, 512 threads = 8 waves; wave wv owns keys c=8wv..8wv+7,
// thread holds its e-quad: kreg[8] = 32 VGPRs. NO min-waves/waves_per_eu hints:
// rounds 3-5 showed any min-waves request W makes the allocator cap at 256/W
// VGPRs and spill kreg to scratch (+84..520 MB HBM). Plain launch_bounds lets
// it allocate the ~60 it needs (round 1/2 precedent: spill-free). Peak live
// ~58 regs; if <=64 -> 8 waves/SIMD, LDS 20.6 KB -> 4 blocks/CU -> 32 waves/CU.
__global__ __launch_bounds__(512) void fused_row(
    const float* __restrict__ x, const float* __restrict__ w2g,
    const float* __restrict__ vals, float* __restrict__ out) {
  __shared__ float att_t[kNC * 9];        // [c][h] stride 9: conflict-free gather
  __shared__ float cw[kNC * kNH];         // [c][h], 2 KB
  __shared__ float4 part[8 * 2 * 64];     // [slot][head2][equad], 16 KB (reused x4)

  const int tid  = threadIdx.x;
  const int wv   = tid >> 6;
  const int lane = tid & 63;
  const int r    = blockIdx.x;

  const float* __restrict__ xrow = x + (size_t)r * kXRow;
  float* __restrict__ orow       = out + (size_t)r * kORow;
  const float4* __restrict__ x4  = reinterpret_cast<const float4*>(xrow);
  float4* __restrict__ o4        = reinterpret_cast<float4*>(orow);

  // ---- phase A: single coalesced read; copy -> out; keys -> regs; att fused.
  //      Lane's w2 quad from global (L2-hot broadcast): head h = lane>>3,
  //      dims 4*(lane&7)..+3; 3-level shfl reduces over lane&7.
  float4 kreg[8];
  const float4 wq = reinterpret_cast<const float4*>(w2g)[lane];
  if (wv == 0) o4[lane] = x4[lane];     // field 0: copy only (not a key)
#pragma unroll
  for (int j = 0; j < 8; ++j) {
    const int c = wv * 8 + j;           // key index; field f = c+1
    const float4 v = x4[(c + 1) * 64 + lane];
    o4[(c + 1) * 64 + lane] = v;
    kreg[j] = v;
    float p = v.x * wq.x + v.y * wq.y + v.z * wq.z + v.w * wq.w;
    p += __shfl_xor(p, 1);
    p += __shfl_xor(p, 2);
    p += __shfl_xor(p, 4);
    if ((lane & 7) == 0) att_t[c * 9 + (lane >> 3)] = p * 0.03125f;
  }
  __syncthreads();

  // ---- entmax-1.5 bisection, run redundantly by ALL 8 waves (identical
  //      inputs/ops -> bitwise-identical results; cw writes are a benign
  //      identical-value race; each wave reads back only values it also wrote
  //      itself, so no barrier before phase C). lane = h*8+kk, 8 c's/lane.
  {
    const int h  = lane >> 3;
    const int kk = lane & 7;
    float X[8];
#pragma unroll
    for (int j = 0; j < 8; ++j) X[j] = att_t[(kk * 8 + j) * 9 + h];

    float mx = X[0];
#pragma unroll
    for (int j = 1; j < 8; ++j) mx = fmaxf(mx, X[j]);
    mx = fmaxf(mx, __shfl_xor(mx, 1));
    mx = fmaxf(mx, __shfl_xor(mx, 2));
    mx = fmaxf(mx, __shfl_xor(mx, 4));

    float tau_lo = mx - 1.0f;       // _gp(1, 1.5) = 1
    float dm     = 0.875f;          // 1 - (1/64)^0.5
    float f_lo = 0.f;
#pragma unroll
    for (int j = 0; j < 8; ++j) {
      float t = fmaxf(X[j] - tau_lo, 0.f);
      f_lo += t * t;
    }
    f_lo += __shfl_xor(f_lo, 1);
    f_lo += __shfl_xor(f_lo, 2);
    f_lo += __shfl_xor(f_lo, 4);
    f_lo -= 1.0f;

    float tau_m = tau_lo;
    for (int it = 0; it < 50; ++it) {
      dm *= 0.5f;
      tau_m = tau_lo + dm;
      float fm = 0.f;
#pragma unroll
      for (int j = 0; j < 8; ++j) {
        float t = fmaxf(X[j] - tau_m, 0.f);
        fm += t * t;
      }
      fm += __shfl_xor(fm, 1);
      fm += __shfl_xor(fm, 2);
      fm += __shfl_xor(fm, 4);
      fm -= 1.0f;
      tau_lo = (fm * f_lo >= 0.f) ? tau_m : tau_lo;
      // fp32 fixed point: once tau_lo + dm/2 rounds to tau_lo for every lane,
      // all remaining reference iterations are bitwise no-ops with final
      // tau_m == tau_lo. Exact fp32 semantics preserved (verified rounds 1-5).
      if (__all(tau_lo + dm * 0.5f == tau_lo)) {
        tau_m = tau_lo;
        break;
      }
    }

    float s = 0.f;
    float p[8];
#pragma unroll
    for (int j = 0; j < 8; ++j) {
      float t = fmaxf(X[j] - tau_m, 0.f);
      p[j] = t * t;
      s += p[j];
    }
    s += __shfl_xor(s, 1);
    s += __shfl_xor(s, 2);
    s += __shfl_xor(s, 4);
    const float inv = 1.0f / s;
    const float* __restrict__ vrow = vals + h * kNC + kk * 8;   // L2-hot
#pragma unroll
    for (int j = 0; j < 8; ++j) {
      cw[(kk * 8 + j) * kNH + h] = p[j] * inv * vrow[j];
    }
  }
  // no barrier: each wave reads back only cw values it wrote itself.

  // ---- phase C: 4 passes of 2 heads through a reused 16 KB partial buffer.
  //      Per pass: per-wave partials from register keys -> part[wv] ->
  //      barrier -> 512-thread scalar sum of 8 slots + exp + store.
  const float2* __restrict__ cw2 = reinterpret_cast<const float2*>(cw);
  const float* partf             = reinterpret_cast<const float*>(part);
#pragma unroll
  for (int hh = 0; hh < 4; ++hh) {
    float4 a0 = make_float4(0.f, 0.f, 0.f, 0.f);
    float4 a1 = make_float4(0.f, 0.f, 0.f, 0.f);
#pragma unroll
    for (int j = 0; j < 8; ++j) {
      const float4 kv = kreg[j];
      const float2 ca = cw2[(wv * 8 + j) * 4 + hh];   // broadcast: heads 2hh,2hh+1
      a0.x += ca.x * kv.x; a0.y += ca.x * kv.y; a0.z += ca.x * kv.z; a0.w += ca.x * kv.w;
      a1.x += ca.y * kv.x; a1.y += ca.y * kv.y; a1.z += ca.y * kv.z; a1.w += ca.y * kv.w;
    }
    part[wv * 128 + lane]      = a0;   // lane-consecutive float4, conflict-free
    part[wv * 128 + 64 + lane] = a1;
    __syncthreads();
    {
      float s = partf[tid];
#pragma unroll
      for (int sl = 1; sl < 8; ++sl) s += partf[sl * 512 + tid];
      orow[kXRow + hh * 512 + tid] = expf(s);   // consecutive floats: coalesced
    }
    __syncthreads();   // protect part reuse by next pass
  }
}

}  // namespace

extern "C" void kernel_launch(void* const* d_in, const int* in_sizes, int n_in,
                              void* d_out, int out_size, void* d_ws, size_t ws_size,
                              hipStream_t stream) {
  const float* x     = reinterpret_cast<const float*>(d_in[0]);
  const float* bw    = reinterpret_cast<const float*>(d_in[1]);
  const float* query = reinterpret_cast<const float*>(d_in[2]);
  const float* vals  = reinterpret_cast<const float*>(d_in[3]);
  float* out = reinterpret_cast<float*>(d_out);
  float* w2  = reinterpret_cast<float*>(d_ws);   // 256 floats of scratch

  hipLaunchKernelGGL(w2_precompute, dim3(1), dim3(256), 0, stream, bw, query, w2);
  hipLaunchKernelGGL(fused_row, dim3(kRows), dim3(512), 0, stream, x, w2, vals, out);
}

// Round 8
// 120.904 us; speedup vs baseline: 3.1798x; 1.2151x over previous
//
#include <hip/hip_runtime.h>
#include <math.h>

namespace {

constexpr int kRows = 4096;
constexpr int kNF   = 65;
constexpr int kNE   = 256;
constexpr int kNH   = 8;
constexpr int kNC   = 64;                  // kNF - 1 fields used
constexpr int kXRow = kNF * kNE;           // 16640 floats per x row
constexpr int kORow = (kNF + kNH) * kNE;   // 18688 floats per out row

typedef float vf4 __attribute__((ext_vector_type(4)));  // NT-store-compatible

__device__ __forceinline__ void nt_store4(const float4& v, float4* dst) {
  vf4 t = {v.x, v.y, v.z, v.w};
  __builtin_nontemporal_store(t, reinterpret_cast<vf4*>(dst));
}

// w2[h*32+d] = sum_k bw[h,d,k] * query[h,k]
__global__ __launch_bounds__(256) void w2_precompute(
    const float* __restrict__ bw, const float* __restrict__ query,
    float* __restrict__ w2) {
  const int t = threadIdx.x;         // t = h*32 + d
  const int h = t >> 5;
  const float4* __restrict__ b4 = reinterpret_cast<const float4*>(bw) + (size_t)t * 64;
  const float4* __restrict__ q4 = reinterpret_cast<const float4*>(query) + (size_t)h * 64;
  float acc = 0.f;
#pragma unroll 8
  for (int k = 0; k < 64; ++k) {
    const float4 b = b4[k];
    const float4 q = q4[k];
    acc += b.x * q.x + b.y * q.y + b.z * q.z + b.w * q.w;
  }
  w2[t] = acc;
}

// One block = one row, 512 threads = 8 waves; wave wv owns keys c=8wv..8wv+7,
// thread holds its e-quad: kreg[8] = 32 VGPRs. No min-waves hints (rounds 3-5:
// any min-waves request W caps the allocator at 256/W VGPRs and spills kreg).
// Round 7/8: (1) non-temporal stores for ALL out writes — out is write-once,
// never re-read in-kernel; NT keeps x L3-resident across replays (round-4
// FETCH 167 MB < 273 MB showed partial retention; NT protects it).
// (2) loads issued before any dependent store/dot (max MLP). (3) __expf.
__global__ __launch_bounds__(512) void fused_row(
    const float* __restrict__ x, const float* __restrict__ w2g,
    const float* __restrict__ vals, float* __restrict__ out) {
  __shared__ float att_t[kNC * 9];        // [c][h] stride 9: conflict-free gather
  __shared__ float cw[kNC * kNH];         // [c][h], 2 KB
  __shared__ float4 part[8 * 2 * 64];     // [slot][head2][equad], 16 KB (reused x4)

  const int tid  = threadIdx.x;
  const int wv   = tid >> 6;
  const int lane = tid & 63;
  const int r    = blockIdx.x;

  const float* __restrict__ xrow = x + (size_t)r * kXRow;
  float* __restrict__ orow       = out + (size_t)r * kORow;
  const float4* __restrict__ x4  = reinterpret_cast<const float4*>(xrow);
  float4* __restrict__ o4        = reinterpret_cast<float4*>(orow);

  // ---- phase A: issue ALL loads first (8-9 outstanding vmem per wave), then
  //      copy -> out (NT) + att dot + 3-level shfl reduce over lane&7.
  //      Lane's w2 quad: head h = lane>>3, dims 4*(lane&7)..+3.
  float4 kreg[8];
  const float4 wq = reinterpret_cast<const float4*>(w2g)[lane];
  float4 v0;
  if (wv == 0) v0 = x4[lane];           // field 0: copy only (not a key)
#pragma unroll
  for (int j = 0; j < 8; ++j) {
    kreg[j] = x4[(wv * 8 + j + 1) * 64 + lane];
  }
  if (wv == 0) nt_store4(v0, &o4[lane]);
#pragma unroll
  for (int j = 0; j < 8; ++j) {
    const int c = wv * 8 + j;           // key index; field f = c+1
    const float4 v = kreg[j];
    nt_store4(v, &o4[(c + 1) * 64 + lane]);
    float p = v.x * wq.x + v.y * wq.y + v.z * wq.z + v.w * wq.w;
    p += __shfl_xor(p, 1);
    p += __shfl_xor(p, 2);
    p += __shfl_xor(p, 4);
    if ((lane & 7) == 0) att_t[c * 9 + (lane >> 3)] = p * 0.03125f;
  }
  __syncthreads();

  // ---- entmax-1.5 bisection, run redundantly by ALL 8 waves (identical
  //      inputs/ops -> bitwise-identical results; cw writes are a benign
  //      identical-value race; each wave reads back only values it also wrote
  //      itself, so no barrier before phase C). lane = h*8+kk, 8 c's/lane.
  {
    const int h  = lane >> 3;
    const int kk = lane & 7;
    float X[8];
#pragma unroll
    for (int j = 0; j < 8; ++j) X[j] = att_t[(kk * 8 + j) * 9 + h];

    float mx = X[0];
#pragma unroll
    for (int j = 1; j < 8; ++j) mx = fmaxf(mx, X[j]);
    mx = fmaxf(mx, __shfl_xor(mx, 1));
    mx = fmaxf(mx, __shfl_xor(mx, 2));
    mx = fmaxf(mx, __shfl_xor(mx, 4));

    float tau_lo = mx - 1.0f;       // _gp(1, 1.5) = 1
    float dm     = 0.875f;          // 1 - (1/64)^0.5
    float f_lo = 0.f;
#pragma unroll
    for (int j = 0; j < 8; ++j) {
      float t = fmaxf(X[j] - tau_lo, 0.f);
      f_lo += t * t;
    }
    f_lo += __shfl_xor(f_lo, 1);
    f_lo += __shfl_xor(f_lo, 2);
    f_lo += __shfl_xor(f_lo, 4);
    f_lo -= 1.0f;

    float tau_m = tau_lo;
    for (int it = 0; it < 50; ++it) {
      dm *= 0.5f;
      tau_m = tau_lo + dm;
      float fm = 0.f;
#pragma unroll
      for (int j = 0; j < 8; ++j) {
        float t = fmaxf(X[j] - tau_m, 0.f);
        fm += t * t;
      }
      fm += __shfl_xor(fm, 1);
      fm += __shfl_xor(fm, 2);
      fm += __shfl_xor(fm, 4);
      fm -= 1.0f;
      tau_lo = (fm * f_lo >= 0.f) ? tau_m : tau_lo;
      // fp32 fixed point: once tau_lo + dm/2 rounds to tau_lo for every lane,
      // all remaining reference iterations are bitwise no-ops with final
      // tau_m == tau_lo. Exact fp32 semantics preserved (verified rounds 1-6).
      if (__all(tau_lo + dm * 0.5f == tau_lo)) {
        tau_m = tau_lo;
        break;
      }
    }

    float s = 0.f;
    float p[8];
#pragma unroll
    for (int j = 0; j < 8; ++j) {
      float t = fmaxf(X[j] - tau_m, 0.f);
      p[j] = t * t;
      s += p[j];
    }
    s += __shfl_xor(s, 1);
    s += __shfl_xor(s, 2);
    s += __shfl_xor(s, 4);
    const float inv = 1.0f / s;
    const float* __restrict__ vrow = vals + h * kNC + kk * 8;   // L2-hot
#pragma unroll
    for (int j = 0; j < 8; ++j) {
      cw[(kk * 8 + j) * kNH + h] = p[j] * inv * vrow[j];
    }
  }
  // no barrier: each wave reads back only cw values it wrote itself.

  // ---- phase C: 4 passes of 2 heads through a reused 16 KB partial buffer.
  //      Per pass: per-wave partials from register keys -> part[wv] ->
  //      barrier -> 512-thread scalar sum of 8 slots + __expf + NT store.
  const float2* __restrict__ cw2 = reinterpret_cast<const float2*>(cw);
  const float* partf             = reinterpret_cast<const float*>(part);
#pragma unroll
  for (int hh = 0; hh < 4; ++hh) {
    float4 a0 = make_float4(0.f, 0.f, 0.f, 0.f);
    float4 a1 = make_float4(0.f, 0.f, 0.f, 0.f);
#pragma unroll
    for (int j = 0; j < 8; ++j) {
      const float4 kv = kreg[j];
      const float2 ca = cw2[(wv * 8 + j) * 4 + hh];   // broadcast: heads 2hh,2hh+1
      a0.x += ca.x * kv.x; a0.y += ca.x * kv.y; a0.z += ca.x * kv.z; a0.w += ca.x * kv.w;
      a1.x += ca.y * kv.x; a1.y += ca.y * kv.y; a1.z += ca.y * kv.z; a1.w += ca.y * kv.w;
    }
    part[wv * 128 + lane]      = a0;   // lane-consecutive float4, conflict-free
    part[wv * 128 + 64 + lane] = a1;
    __syncthreads();
    {
      float s = partf[tid];
#pragma unroll
      for (int sl = 1; sl < 8; ++sl) s += partf[sl * 512 + tid];
      __builtin_nontemporal_store(__expf(s), &orow[kXRow + hh * 512 + tid]);
    }
    __syncthreads();   // protect part reuse by next pass
  }
}

}  // namespace

extern "C" void kernel_launch(void* const* d_in, const int* in_sizes, int n_in,
                              void* d_out, int out_size, void* d_ws, size_t ws_size,
                              hipStream_t stream) {
  const float* x     = reinterpret_cast<const float*>(d_in[0]);
  const float* bw    = reinterpret_cast<const float*>(d_in[1]);
  const float* query = reinterpret_cast<const float*>(d_in[2]);
  const float* vals  = reinterpret_cast<const float*>(d_in[3]);
  float* out = reinterpret_cast<float*>(d_out);
  float* w2  = reinterpret_cast<float*>(d_ws);   // 256 floats of scratch

  hipLaunchKernelGGL(w2_precompute, dim3(1), dim3(256), 0, stream, bw, query, w2);
  hipLaunchKernelGGL(fused_row, dim3(kRows), dim3(512), 0, stream, x, w2, vals, out);
}

// Round 9
// 107.634 us; speedup vs baseline: 3.5718x; 1.1233x over previous
//
#include <hip/hip_runtime.h>
#include <math.h>

namespace {

constexpr int kRows = 4096;
constexpr int kNF   = 65;
constexpr int kNE   = 256;
constexpr int kNH   = 8;
constexpr int kNC   = 64;                  // kNF - 1 fields used
constexpr int kXRow = kNF * kNE;           // 16640 floats per x row
constexpr int kORow = (kNF + kNH) * kNE;   // 18688 floats per out row

typedef float vf4 __attribute__((ext_vector_type(4)));  // NT-store-compatible

__device__ __forceinline__ void nt_store4(const float4& v, float4* dst) {
  vf4 t = {v.x, v.y, v.z, v.w};
  __builtin_nontemporal_store(t, reinterpret_cast<vf4*>(dst));
}

// w2[t] = sum_k bw[t*256+k] * query[(t>>5)*256+k].  32 blocks x 256 threads:
// block b owns outputs t = 8b..8b+7 (reads its bw slice exactly once; the old
// 1-block version serialized the whole GPU for ~5 us per replay).
__global__ __launch_bounds__(256) void w2_precompute(
    const float* __restrict__ bw, const float* __restrict__ query,
    float* __restrict__ w2) {
  const int o = threadIdx.x >> 5;          // 0..7: which of this block's outputs
  const int l = threadIdx.x & 31;          // 32 lanes per output
  const int t = blockIdx.x * 8 + o;
  const int h = t >> 5;
  const float4* __restrict__ bp =
      reinterpret_cast<const float4*>(bw + (size_t)t * 256 + l * 8);
  const float4* __restrict__ qp =
      reinterpret_cast<const float4*>(query + (size_t)h * 256 + l * 8);
  const float4 b0 = bp[0], b1 = bp[1];
  const float4 q0 = qp[0], q1 = qp[1];
  float acc = b0.x * q0.x + b0.y * q0.y + b0.z * q0.z + b0.w * q0.w
            + b1.x * q1.x + b1.y * q1.y + b1.z * q1.z + b1.w * q1.w;
  acc += __shfl_xor(acc, 1);
  acc += __shfl_xor(acc, 2);
  acc += __shfl_xor(acc, 4);
  acc += __shfl_xor(acc, 8);
  acc += __shfl_xor(acc, 16);
  if (l == 0) w2[t] = acc;
}

// One block = one row, 512 threads = 8 waves; wave wv owns keys c=8wv..8wv+7.
// No min-waves hints (rounds 3-5: any min-waves request W caps the allocator
// at 256/W VGPRs and spills). Round-8 learning: the allocator rematerializes
// phase-C key loads from global (L2/L3-hot) rather than holding kreg live —
// VGPR 36, no scratch, FETCH stays ~133 MB. NT stores for all out writes.
// Round 9: Newton (~8 iter) replaces bisection (~24) for the entmax root —
// same fp32 fixed point, half the serial chain; phase C in 2 passes of 4
// heads (barriers 9 -> 4).
__global__ __launch_bounds__(512) void fused_row(
    const float* __restrict__ x, const float* __restrict__ w2g,
    const float* __restrict__ vals, float* __restrict__ out) {
  __shared__ float att_t[kNC * 9];        // [c][h] stride 9: conflict-free gather
  __shared__ float cw[kNC * kNH];         // [c][h], 2 KB
  __shared__ float4 part[8 * 4 * 64];     // [slot][head4][equad], 32 KB (reused x2)

  const int tid  = threadIdx.x;
  const int wv   = tid >> 6;
  const int lane = tid & 63;
  const int r    = blockIdx.x;

  const float* __restrict__ xrow = x + (size_t)r * kXRow;
  float* __restrict__ orow       = out + (size_t)r * kORow;
  const float4* __restrict__ x4  = reinterpret_cast<const float4*>(xrow);
  float4* __restrict__ o4        = reinterpret_cast<float4*>(orow);

  // ---- phase A: issue ALL loads first (9 outstanding vmem per wave), then
  //      copy -> out (NT) + att dot + 3-level shfl reduce over lane&7.
  //      Lane's w2 quad: head h = lane>>3, dims 4*(lane&7)..+3.
  float4 kreg[8];
  const float4 wq = reinterpret_cast<const float4*>(w2g)[lane];
  float4 v0;
  if (wv == 0) v0 = x4[lane];           // field 0: copy only (not a key)
#pragma unroll
  for (int j = 0; j < 8; ++j) {
    kreg[j] = x4[(wv * 8 + j + 1) * 64 + lane];
  }
  if (wv == 0) nt_store4(v0, &o4[lane]);
#pragma unroll
  for (int j = 0; j < 8; ++j) {
    const int c = wv * 8 + j;           // key index; field f = c+1
    const float4 v = kreg[j];
    nt_store4(v, &o4[(c + 1) * 64 + lane]);
    float p = v.x * wq.x + v.y * wq.y + v.z * wq.z + v.w * wq.w;
    p += __shfl_xor(p, 1);
    p += __shfl_xor(p, 2);
    p += __shfl_xor(p, 4);
    if ((lane & 7) == 0) att_t[c * 9 + (lane >> 3)] = p * 0.03125f;
  }
  __syncthreads();

  // ---- entmax-1.5 via Newton on f(tau) = sum clip(X-tau)^2 - 1 (convex,
  //      decreasing, |f'| >= 2 near root). tau0 = mx-1 has f >= 0; Newton
  //      converges monotonically from below to the same fp32 fixed point the
  //      reference's 50-iter bisection lands on (tau within 8e-16 of exact;
  //      gates are normalized afterwards -> O(ulp) output difference, with
  //      14x measured threshold headroom). Run redundantly by ALL 8 waves
  //      (identical inputs/ops -> bitwise-identical; cw writes are a benign
  //      identical-value race; each wave reads back only its own writes, so
  //      no barrier before phase C). lane = h*8+kk, 8 c's per lane.
  {
    const int h  = lane >> 3;
    const int kk = lane & 7;
    float X[8];
#pragma unroll
    for (int j = 0; j < 8; ++j) X[j] = att_t[(kk * 8 + j) * 9 + h];

    float mx = X[0];
#pragma unroll
    for (int j = 1; j < 8; ++j) mx = fmaxf(mx, X[j]);
    mx = fmaxf(mx, __shfl_xor(mx, 1));
    mx = fmaxf(mx, __shfl_xor(mx, 2));
    mx = fmaxf(mx, __shfl_xor(mx, 4));

    float tau = mx - 1.0f;            // f(tau0) >= 0 (largest clip term = 1)
    for (int it = 0; it < 16; ++it) {
      float s2 = 0.f, s1 = 0.f;
#pragma unroll
      for (int j = 0; j < 8; ++j) {
        const float t = fmaxf(X[j] - tau, 0.f);
        s2 += t * t;
        s1 += t;
      }
      s2 += __shfl_xor(s2, 1); s1 += __shfl_xor(s1, 1);
      s2 += __shfl_xor(s2, 2); s1 += __shfl_xor(s1, 2);
      s2 += __shfl_xor(s2, 4); s1 += __shfl_xor(s1, 4);
      const float delta = (s2 - 1.0f) / (2.0f * fmaxf(s1, 1e-30f));
      const float ntau = tau + delta;
      if (__all(ntau == tau)) break;   // fp32 fixed point reached
      tau = ntau;
    }

    float s = 0.f;
    float p[8];
#pragma unroll
    for (int j = 0; j < 8; ++j) {
      const float t = fmaxf(X[j] - tau, 0.f);
      p[j] = t * t;
      s += p[j];
    }
    s += __shfl_xor(s, 1);
    s += __shfl_xor(s, 2);
    s += __shfl_xor(s, 4);
    const float inv = 1.0f / s;
    const float* __restrict__ vrow = vals + h * kNC + kk * 8;   // L2-hot
#pragma unroll
    for (int j = 0; j < 8; ++j) {
      cw[(kk * 8 + j) * kNH + h] = p[j] * inv * vrow[j];
    }
  }
  // no barrier: each wave reads back only cw values it wrote itself.

  // ---- phase C: 2 passes of 4 heads through a reused 32 KB partial buffer.
  //      Per pass: per-wave partials from (rematerialized) key quads ->
  //      part[wv] -> barrier -> 512-thread scalar sum of 8 slots + __expf +
  //      NT store. cw4[c*2+hh] = heads 4hh..4hh+3 of key c (broadcast read).
  const float4* __restrict__ cw4 = reinterpret_cast<const float4*>(cw);
  const float* partf             = reinterpret_cast<const float*>(part);
#pragma unroll
  for (int hh = 0; hh < 2; ++hh) {
    float4 a0 = make_float4(0.f, 0.f, 0.f, 0.f);
    float4 a1 = make_float4(0.f, 0.f, 0.f, 0.f);
    float4 a2 = make_float4(0.f, 0.f, 0.f, 0.f);
    float4 a3 = make_float4(0.f, 0.f, 0.f, 0.f);
#pragma unroll
    for (int j = 0; j < 8; ++j) {
      const float4 kv = kreg[j];
      const float4 ca = cw4[(wv * 8 + j) * 2 + hh];
      a0.x += ca.x * kv.x; a0.y += ca.x * kv.y; a0.z += ca.x * kv.z; a0.w += ca.x * kv.w;
      a1.x += ca.y * kv.x; a1.y += ca.y * kv.y; a1.z += ca.y * kv.z; a1.w += ca.y * kv.w;
      a2.x += ca.z * kv.x; a2.y += ca.z * kv.y; a2.z += ca.z * kv.z; a2.w += ca.z * kv.w;
      a3.x += ca.w * kv.x; a3.y += ca.w * kv.y; a3.z += ca.w * kv.z; a3.w += ca.w * kv.w;
    }
    part[wv * 256 + 0 * 64 + lane] = a0;   // lane-consecutive, conflict-free
    part[wv * 256 + 1 * 64 + lane] = a1;
    part[wv * 256 + 2 * 64 + lane] = a2;
    part[wv * 256 + 3 * 64 + lane] = a3;
    __syncthreads();
#pragma unroll
    for (int oo = 0; oo < 2; ++oo) {
      const int o = oo * 512 + tid;        // o = head4*256 + e within this pass
      float s = partf[o];
#pragma unroll
      for (int sl = 1; sl < 8; ++sl) s += partf[sl * 1024 + o];
      __builtin_nontemporal_store(__expf(s), &orow[kXRow + hh * 1024 + o]);
    }
    if (hh == 0) __syncthreads();          // protect part reuse by pass 2
  }
}

}  // namespace

extern "C" void kernel_launch(void* const* d_in, const int* in_sizes, int n_in,
                              void* d_out, int out_size, void* d_ws, size_t ws_size,
                              hipStream_t stream) {
  const float* x     = reinterpret_cast<const float*>(d_in[0]);
  const float* bw    = reinterpret_cast<const float*>(d_in[1]);
  const float* query = reinterpret_cast<const float*>(d_in[2]);
  const float* vals  = reinterpret_cast<const float*>(d_in[3]);
  float* out = reinterpret_cast<float*>(d_out);
  float* w2  = reinterpret_cast<float*>(d_ws);   // 256 floats of scratch

  hipLaunchKernelGGL(w2_precompute, dim3(32), dim3(256), 0, stream, bw, query, w2);
  hipLaunchKernelGGL(fused_row, dim3(kRows), dim3(512), 0, stream, x, w2, vals, out);
}